// Round 2
// baseline (213.778 us; speedup 1.0000x reference)
//
#include <hip/hip_runtime.h>
#include <math.h>

#define B_DIM 4
#define N_DIM 8192
#define C_DIM 256
#define H_DIM 8
#define D_DIM 32
#define TM 32           // rows per block in K1
#define RP 36           // padded row stride (floats); 36*4=144 B keeps 16-B alignment per k-row
#define LN_EPS 1e-5f

// ---------------------------------------------------------------------------
// K1: per 32-row tile: Uk = U@Wk, Uv = U@Wv (f32), LayerNorm over 256 cols,
//     s[h] = <Wq[h,:],Uk_ln[h,:]>, partial qk += s*Uv_ln. Thread t owns column
//     t of both Uk and Uv; ALL 32 rows accumulate in registers so Wk/Wv are
//     streamed exactly once per block. float2 accumulators -> v_pk_fma_f32.
// ---------------------------------------------------------------------------
__global__ __launch_bounds__(256, 4)
void k1_gemm_ln_reduce(const float* __restrict__ U,
                       const float* __restrict__ Wq,
                       const float* __restrict__ Wk,
                       const float* __restrict__ Wv,
                       const float* __restrict__ gamma,
                       const float* __restrict__ beta,
                       float* __restrict__ part)   // [gridDim.x][256]
{
    __shared__ float Ut[C_DIM * RP];   // transposed tile: Ut[k*RP + r]
    __shared__ float red[4][TM][4];    // cross-wave stat partials (2 KB)

    const int t = threadIdx.x;
    const int bid = blockIdx.x;
    const int tiles_per_b = N_DIM / TM;           // 256
    const int b = bid / tiles_per_b;
    const int row0 = (bid % tiles_per_b) * TM;

    const float* __restrict__ Ub = U + ((size_t)b * N_DIM + row0) * C_DIM;

    // stage U tile transposed (coalesced global read; 4-way LDS write conflict, once)
    #pragma unroll 8
    for (int r = 0; r < TM; ++r) {
        Ut[t * RP + r] = Ub[(size_t)r * C_DIM + t];
    }
    __syncthreads();

    const int wave = t >> 6;
    const int lane = t & 63;

    const float wq = Wq[t];       // Wq flat [H*D] = [256]
    const float g  = gamma[t];
    const float be = beta[t];

    const float* __restrict__ wk_col = Wk + t;    // Wk[k*256 + t]
    const float* __restrict__ wv_col = Wv + t;

    float2 ak[TM / 2], av[TM / 2];
    #pragma unroll
    for (int i = 0; i < TM / 2; ++i) {
        ak[i] = make_float2(0.f, 0.f);
        av[i] = make_float2(0.f, 0.f);
    }

    // GEMM: per k: 2 coalesced W loads + 8 ds_read_b128 (broadcast) + 32 pk-FMA
    #pragma unroll 4
    for (int k = 0; k < C_DIM; ++k) {
        const float wk = wk_col[(size_t)k * C_DIM];
        const float wv = wv_col[(size_t)k * C_DIM];
        const float2* __restrict__ up = (const float2*)&Ut[k * RP];
        #pragma unroll
        for (int i = 0; i < TM / 2; ++i) {
            const float2 u = up[i];
            ak[i].x = fmaf(u.x, wk, ak[i].x);
            ak[i].y = fmaf(u.y, wk, ak[i].y);
            av[i].x = fmaf(u.x, wv, av[i].x);
            av[i].y = fmaf(u.y, wv, av[i].y);
        }
    }

    const float* akf = reinterpret_cast<const float*>(ak);
    const float* avf = reinterpret_cast<const float*>(av);

    // per-row stats (sum, sumsq for k and v) across the 256 threads
    #pragma unroll 4
    for (int r = 0; r < TM; ++r) {
        const float a = akf[r], v = avf[r];
        float s0 = a, s1 = a * a, s2 = v, s3 = v * v;
        #pragma unroll
        for (int m = 1; m <= 32; m <<= 1) {
            s0 += __shfl_xor(s0, m, 64);
            s1 += __shfl_xor(s1, m, 64);
            s2 += __shfl_xor(s2, m, 64);
            s3 += __shfl_xor(s3, m, 64);
        }
        if (lane == 0) {
            red[wave][r][0] = s0; red[wave][r][1] = s1;
            red[wave][r][2] = s2; red[wave][r][3] = s3;
        }
    }
    __syncthreads();

    float qk_acc = 0.f;
    #pragma unroll 4
    for (int r = 0; r < TM; ++r) {
        const float sk  = red[0][r][0] + red[1][r][0] + red[2][r][0] + red[3][r][0];
        const float qkk = red[0][r][1] + red[1][r][1] + red[2][r][1] + red[3][r][1];
        const float sv  = red[0][r][2] + red[1][r][2] + red[2][r][2] + red[3][r][2];
        const float qvv = red[0][r][3] + red[1][r][3] + red[2][r][3] + red[3][r][3];

        const float muk  = sk * (1.f / 256.f);
        const float vark = qkk * (1.f / 256.f) - muk * muk;
        const float rsk  = 1.0f / sqrtf(vark + LN_EPS);
        const float muv  = sv * (1.f / 256.f);
        const float varv = qvv * (1.f / 256.f) - muv * muv;
        const float rsv  = 1.0f / sqrtf(varv + LN_EPS);

        const float lnk = (akf[r] - muk) * rsk * g + be;
        const float lnv = (avf[r] - muv) * rsv * g + be;

        // s[h]: sum over the 32 lanes of this head group (t/32 = h)
        float p = wq * lnk;
        #pragma unroll
        for (int m = 1; m <= 16; m <<= 1) p += __shfl_xor(p, m, 64);

        qk_acc = fmaf(p, lnv, qk_acc);
    }

    part[(size_t)bid * 256 + t] = qk_acc;
}

// ---------------------------------------------------------------------------
// K2: reduce 256 block-partials per batch -> qk[b][t]  (t = h*32+e)
// ---------------------------------------------------------------------------
__global__ void k2_reduce(const float* __restrict__ part, float* __restrict__ qk)
{
    const int b = blockIdx.x;
    const int t = threadIdx.x;
    const int np = (N_DIM / TM);                     // 256 partials per batch
    const float* __restrict__ p = part + (size_t)b * np * 256 + t;
    float s = 0.f;
    for (int i = 0; i < np; ++i) s += p[(size_t)i * 256];
    qk[b * 256 + t] = s;
}

// ---------------------------------------------------------------------------
// K3: out[b,n,e*H+h] = X[b,n] * qk[b,h*32+e] / N   (33.5 MB write, BW-bound)
// ---------------------------------------------------------------------------
__global__ __launch_bounds__(256)
void k3_out(const float* __restrict__ X, const float* __restrict__ qk,
            float* __restrict__ out)
{
    __shared__ float qkp[256];   // permuted + prescaled: qkp[e*8+h]
    const int t = threadIdx.x;
    const int bid = blockIdx.x;
    const int rows_per_block = 32;
    const int tiles_per_b = N_DIM / rows_per_block;   // 256
    const int b = bid / tiles_per_b;
    const int row0 = (bid % tiles_per_b) * rows_per_block;

    {
        const int h = t & 7;
        const int e = t >> 3;
        qkp[t] = qk[b * 256 + h * 32 + e] * (1.0f / (float)N_DIM);
    }
    __syncthreads();

    const int c4 = (t & 63) * 4;
    const float4 q4 = *(const float4*)&qkp[c4];
    const int rl = t >> 6;

    for (int it = 0; it < rows_per_block / 4; ++it) {
        const int row = row0 + it * 4 + rl;
        const float x = X[(size_t)b * N_DIM + row];
        float4 o;
        o.x = x * q4.x; o.y = x * q4.y; o.z = x * q4.z; o.w = x * q4.w;
        *(float4*)&out[((size_t)b * N_DIM + row) * C_DIM + c4] = o;
    }
}

// ---------------------------------------------------------------------------
extern "C" void kernel_launch(void* const* d_in, const int* in_sizes, int n_in,
                              void* d_out, int out_size, void* d_ws, size_t ws_size,
                              hipStream_t stream)
{
    const float* U     = (const float*)d_in[0];
    const float* X     = (const float*)d_in[1];
    const float* Wq    = (const float*)d_in[2];
    const float* Wk    = (const float*)d_in[3];
    const float* Wv    = (const float*)d_in[4];
    const float* gamma = (const float*)d_in[5];
    const float* beta  = (const float*)d_in[6];
    float* out = (float*)d_out;

    const int n_tiles = B_DIM * (N_DIM / TM);      // 1024
    float* part = (float*)d_ws;                    // [1024][256]
    float* qk   = part + (size_t)n_tiles * 256;    // [4][256]

    k1_gemm_ln_reduce<<<n_tiles, 256, 0, stream>>>(U, Wq, Wk, Wv, gamma, beta, part);
    k2_reduce<<<B_DIM, 256, 0, stream>>>(part, qk);
    k3_out<<<B_DIM * (N_DIM / 32), 256, 0, stream>>>(X, qk, out);
}

// Round 3
// 49.017 us; speedup vs baseline: 4.3613x; 4.3613x over previous
//
#include <hip/hip_runtime.h>
#include <math.h>

#define B_DIM 4
#define N_DIM 8192
#define C_DIM 256
#define LN_EPS 1e-5f
#define WSCALE 4096.0f
#define INV_WSCALE (1.0f/4096.0f)

typedef _Float16 f16x8 __attribute__((ext_vector_type(8)));
typedef _Float16 f16x4 __attribute__((ext_vector_type(4)));
typedef float    f32x4 __attribute__((ext_vector_type(4)));

// ---- workspace layout (bytes) ----
// [0,       262144)  WT packed f16 fragments: chunk cid=(nt*8+kt), lane l: 8 f16
// [262144,  263168)  WG[256]  = Wq*gamma
// [263168,  263200)  K1h[8]   = sum_d Wq*gamma
// [263200,  263232)  K2h[8]   = sum_d Wq*beta
// [264192, 1312768)  part[1024][256] f32
// [1312768, 1316864) qk[4][256] f32
#define WS_WT    0
#define WS_WG    262144
#define WS_K1    263168
#define WS_K2    263200
#define WS_PART  264192
#define WS_QK    1312768

// ---------------------------------------------------------------------------
// K0: pack W into MFMA B-fragment order (f16, scaled by WSCALE) + constants.
// B-frag for 16x16x32: lane l holds B[k][n], n = nt*16+(l&15),
// k = kt*32 + (l>>4)*8 + j, j=0..7. chunk id cid = nt*8+kt, nt 0..31, kt 0..7.
// ---------------------------------------------------------------------------
__global__ void k0_pack_w(const float* __restrict__ Wq,
                          const float* __restrict__ Wk,
                          const float* __restrict__ Wv,
                          const float* __restrict__ gamma,
                          const float* __restrict__ beta,
                          char* __restrict__ ws)
{
    const int t = threadIdx.x;
    if (blockIdx.x < 64) {
        const int gid = blockIdx.x * 256 + t;      // [0, 16384)
        const int l   = gid & 63;
        const int cid = gid >> 6;                  // [0, 256)
        const int nt  = cid >> 3;
        const int kt  = cid & 7;
        const int n   = nt * 16 + (l & 15);
        const int kb  = kt * 32 + ((l >> 4) & 3) * 8;
        const float* __restrict__ Wsrc = (n < 256) ? (Wk + n) : (Wv + (n - 256));
        f16x8 frag;
        #pragma unroll
        for (int j = 0; j < 8; ++j) {
            const float w = Wsrc[(size_t)(kb + j) * C_DIM] * WSCALE;
            frag[j] = (_Float16)w;
        }
        ((f16x8*)(ws + WS_WT))[gid] = frag;
    } else {
        // constants
        if (t < 256) {
            ((float*)(ws + WS_WG))[t] = Wq[t] * gamma[t];
        }
        if (t < 8) {
            float k1 = 0.f, k2 = 0.f;
            for (int d = 0; d < 32; ++d) {
                const int c = t * 32 + d;
                k1 += Wq[c] * gamma[c];
                k2 += Wq[c] * beta[c];
            }
            ((float*)(ws + WS_K1))[t] = k1;
            ((float*)(ws + WS_K2))[t] = k2;
        }
    }
}

// ---------------------------------------------------------------------------
// K1: per 32-row tile: C = [Uk|Uv] via f16 MFMA (f32 accum), then fused
// LayerNorm + s + qk partial. 4 waves; wave w owns cols [w*128, w*128+128).
//
// LDS map (81920 B total, 2 blocks/CU):
//   [0,     65536)  stage f32[32][256] (linear), later C f32[32][512] swizzled:
//                   Cf[r*512 + (c ^ ((r&7)<<2))]
//   [65536, 81920)  A f16[32][256] swizzled (byte ^ ((r&7)<<4));
//                   post-kloop overlay: T[32][8] f32 @+0, red2[32]f4 @+1024,
//                   red3[32]f4 @+1536
// ---------------------------------------------------------------------------
__global__ __launch_bounds__(256, 2)
void k1_mfma_ln_reduce(const float* __restrict__ U,
                       const float* __restrict__ gamma,
                       const float* __restrict__ beta,
                       const char* __restrict__ ws_ro,
                       float* __restrict__ part)
{
    __shared__ char lds[81920];
    float* __restrict__ Cf = (float*)lds;
    char*  __restrict__ Ab = lds + 65536;

    const int t    = threadIdx.x;
    const int lane = t & 63;
    const int w    = t >> 6;
    const int bid  = blockIdx.x;
    const int b    = bid >> 8;
    const int row0 = (bid & 255) * 32;

    // ---- stage U tile (32 rows x 256 cols f32 = 32 KB, contiguous) ----
    {
        const float4* __restrict__ Ug =
            (const float4*)(U + ((size_t)b * N_DIM + row0) * C_DIM);
        float4* __restrict__ S4 = (float4*)lds;
        #pragma unroll
        for (int i = 0; i < 8; ++i) S4[i * 256 + t] = Ug[i * 256 + t];
    }
    __syncthreads();

    // ---- convert to f16 A-tile (swizzled) ----
    {
        const int r  = t >> 3;
        const int cg = t & 7;
        const int swz = (r & 7) << 4;
        const float4* __restrict__ S4 = (const float4*)lds;
        #pragma unroll
        for (int jj = 0; jj < 8; ++jj) {
            const int g = (jj + cg) & 7;                 // rotate: bank spread
            const float4 v = S4[r * 64 + cg * 8 + g];
            f16x4 h;
            h[0] = (_Float16)v.x; h[1] = (_Float16)v.y;
            h[2] = (_Float16)v.z; h[3] = (_Float16)v.w;
            const int byte = r * 512 + cg * 64 + g * 8;
            *(f16x4*)(Ab + (byte ^ swz)) = h;
        }
    }
    __syncthreads();

    // ---- MFMA k-loop: wave w computes rows 0..31 x cols [w*128, w*128+128) ----
    f32x4 acc[2][8];
    #pragma unroll
    for (int m = 0; m < 2; ++m)
        #pragma unroll
        for (int j = 0; j < 8; ++j)
            acc[m][j] = (f32x4)0.0f;

    {
        const f16x8* __restrict__ WT = (const f16x8*)(ws_ro + WS_WT);
        const int l15 = lane & 15;
        const int hi  = (lane >> 4) & 3;
        const int swzA = (l15 & 7) << 4;
        #pragma unroll 2
        for (int kt = 0; kt < 8; ++kt) {
            f16x8 a0 = *(const f16x8*)(Ab + ((0 * 16 + l15) * 512 +
                         ((kt * 64 + hi * 16) ^ swzA)));
            f16x8 a1 = *(const f16x8*)(Ab + ((1 * 16 + l15) * 512 +
                         ((kt * 64 + hi * 16) ^ swzA)));
            #pragma unroll
            for (int j = 0; j < 8; ++j) {
                const f16x8 bfrag = WT[(size_t)(((w * 8 + j) * 8 + kt)) * 64 + lane];
                acc[0][j] = __builtin_amdgcn_mfma_f32_16x16x32_f16(a0, bfrag, acc[0][j], 0, 0, 0);
                acc[1][j] = __builtin_amdgcn_mfma_f32_16x16x32_f16(a1, bfrag, acc[1][j], 0, 0, 0);
            }
        }
    }

    // ---- write C to LDS (f32, /WSCALE, swizzled) ----
    {
        const int l15 = lane & 15;
        const int rg  = (lane >> 4) & 3;
        #pragma unroll
        for (int m = 0; m < 2; ++m)
            #pragma unroll
            for (int j = 0; j < 8; ++j) {
                const int col = (w * 8 + j) * 16 + l15;
                #pragma unroll
                for (int q = 0; q < 4; ++q) {
                    const int row = m * 16 + rg * 4 + q;
                    Cf[row * 512 + (col ^ ((row & 7) << 2))] = acc[m][j][q] * INV_WSCALE;
                }
            }
    }
    __syncthreads();

    // ---- phase 1: per (row r = t>>3, head h = t&7) scan 32 Uk + 32 Uv cols ----
    float* __restrict__ T_lds = (float*)Ab;            // [32][8]
    f32x4* __restrict__ red2  = (f32x4*)(Ab + 1024);   // [32]
    f32x4* __restrict__ red3  = (f32x4*)(Ab + 1536);   // [32]
    {
        const int r = t >> 3;
        const int h = t & 7;
        const float4* __restrict__ C4  = (const float4*)lds;
        const float4* __restrict__ WG4 = (const float4*)(ws_ro + WS_WG);
        float sk = 0.f, qkk = 0.f, sv = 0.f, qvv = 0.f, Tacc = 0.f;
        #pragma unroll
        for (int g = 0; g < 8; ++g) {
            const int jg = (g + h) & 7;                // rotate: bank spread
            const float4 ck = C4[r * 128 + ((h * 8 + jg) ^ (r & 7))];
            const float4 cv = C4[r * 128 + ((64 + h * 8 + jg) ^ (r & 7))];
            const float4 wg = WG4[h * 8 + jg];
            sk  += ck.x + ck.y + ck.z + ck.w;
            qkk += ck.x*ck.x + ck.y*ck.y + ck.z*ck.z + ck.w*ck.w;
            sv  += cv.x + cv.y + cv.z + cv.w;
            qvv += cv.x*cv.x + cv.y*cv.y + cv.z*cv.z + cv.w*cv.w;
            Tacc += wg.x*ck.x + wg.y*ck.y + wg.z*ck.z + wg.w*ck.w;
        }
        #pragma unroll
        for (int m = 1; m <= 4; m <<= 1) {
            sk  += __shfl_xor(sk,  m, 64);
            qkk += __shfl_xor(qkk, m, 64);
            sv  += __shfl_xor(sv,  m, 64);
            qvv += __shfl_xor(qvv, m, 64);
        }
        T_lds[r * 8 + h] = Tacc;
        if (h == 0) { f32x4 v; v[0]=sk; v[1]=qkk; v[2]=sv; v[3]=qvv; red2[r] = v; }
    }
    __syncthreads();

    // ---- phase 1.5: per-row mu / rs ----
    if (t < 32) {
        const f32x4 v = red2[t];
        const float muk  = v[0] * (1.f/256.f);
        const float vark = v[1] * (1.f/256.f) - muk * muk;
        const float rsk  = 1.0f / sqrtf(vark + LN_EPS);
        const float muv  = v[2] * (1.f/256.f);
        const float varv = v[3] * (1.f/256.f) - muv * muv;
        const float rsv  = 1.0f / sqrtf(varv + LN_EPS);
        f32x4 o; o[0]=muk; o[1]=rsk; o[2]=muv; o[3]=rsv;
        red3[t] = o;
    }
    __syncthreads();

    // ---- phase 2: thread t owns Uv col t; qk_acc = sum_r s[r,h] * lnv[r,t] ----
    {
        const int h  = t >> 5;
        const float K1h = ((const float*)(ws_ro + WS_K1))[h];
        const float K2h = ((const float*)(ws_ro + WS_K2))[h];
        const float gv = gamma[t];
        const float bv = beta[t];
        float qk_acc = 0.f;
        #pragma unroll 4
        for (int r = 0; r < 32; ++r) {
            const f32x4 st = red3[r];
            const float Tv = T_lds[r * 8 + h];
            const float s  = st[1] * (Tv - st[0] * K1h) + K2h;
            const float cvv = Cf[r * 512 + ((256 + t) ^ ((r & 7) << 2))];
            const float lnv = (cvv - st[2]) * st[3] * gv + bv;
            qk_acc = fmaf(s, lnv, qk_acc);
        }
        part[(size_t)bid * 256 + t] = qk_acc;
    }
}

// ---------------------------------------------------------------------------
// K2: reduce 256 tile-partials per batch -> qk[b][c]
// grid 32: block = (b = blk>>3, col-group cg = blk&7)
// ---------------------------------------------------------------------------
__global__ void k2_reduce(const float* __restrict__ part, float* __restrict__ qk)
{
    __shared__ float red[8][32];
    const int t   = threadIdx.x;
    const int blk = blockIdx.x;
    const int b   = blk >> 3;
    const int cg  = blk & 7;
    const int c   = cg * 32 + (t & 31);
    const int seg = t >> 5;
    float s = 0.f;
    for (int i = seg * 32; i < seg * 32 + 32; ++i)
        s += part[((size_t)b * 256 + i) * 256 + c];
    red[seg][t & 31] = s;
    __syncthreads();
    if (t < 32) {
        float q = 0.f;
        #pragma unroll
        for (int sgi = 0; sgi < 8; ++sgi) q += red[sgi][t];
        qk[b * 256 + cg * 32 + t] = q;
    }
}

// ---------------------------------------------------------------------------
// K3: out[b,n,e*8+h] = X[b,n] * qk[b,h*32+e] / N   (33.5 MB write, BW-bound)
// ---------------------------------------------------------------------------
__global__ __launch_bounds__(256)
void k3_out(const float* __restrict__ X, const float* __restrict__ qk,
            float* __restrict__ out)
{
    __shared__ float qkp[256];   // permuted + prescaled: qkp[e*8+h]
    const int t = threadIdx.x;
    const int bid = blockIdx.x;
    const int b = bid >> 8;
    const int row0 = (bid & 255) * 32;

    {
        const int h = t & 7;
        const int e = t >> 3;
        qkp[t] = qk[b * 256 + h * 32 + e] * (1.0f / (float)N_DIM);
    }
    __syncthreads();

    const int c4 = (t & 63) * 4;
    const float4 q4 = *(const float4*)&qkp[c4];
    const int rl = t >> 6;

    for (int it = 0; it < 8; ++it) {
        const int row = row0 + it * 4 + rl;
        const float x = X[(size_t)b * N_DIM + row];
        float4 o;
        o.x = x * q4.x; o.y = x * q4.y; o.z = x * q4.z; o.w = x * q4.w;
        *(float4*)&out[((size_t)b * N_DIM + row) * C_DIM + c4] = o;
    }
}

// ---------------------------------------------------------------------------
extern "C" void kernel_launch(void* const* d_in, const int* in_sizes, int n_in,
                              void* d_out, int out_size, void* d_ws, size_t ws_size,
                              hipStream_t stream)
{
    const float* U     = (const float*)d_in[0];
    const float* X     = (const float*)d_in[1];
    const float* Wq    = (const float*)d_in[2];
    const float* Wk    = (const float*)d_in[3];
    const float* Wv    = (const float*)d_in[4];
    const float* gamma = (const float*)d_in[5];
    const float* beta  = (const float*)d_in[6];
    float* out = (float*)d_out;

    char* ws = (char*)d_ws;
    float* part = (float*)(ws + WS_PART);
    float* qk   = (float*)(ws + WS_QK);

    k0_pack_w<<<65, 256, 0, stream>>>(Wq, Wk, Wv, gamma, beta, ws);
    k1_mfma_ln_reduce<<<1024, 256, 0, stream>>>(U, gamma, beta, ws, part);
    k2_reduce<<<32, 256, 0, stream>>>(part, qk);
    k3_out<<<1024, 256, 0, stream>>>(X, qk, out);
}